// Round 1
// baseline (995.159 us; speedup 1.0000x reference)
//
#include <hip/hip_runtime.h>
#include <stdint.h>

#define DIM 512
#define BM 128    // rows per workgroup (fp32 fallback)
#define BK 128    // codebook entries per k-tile (fp32 fallback)
#define BD 32     // D-chunk staged in LDS (fp32 fallback)
#define LDP 132   // padded LDS leading dim (floats, fp32 fallback)
// Flag thresholds: reference distances are quantized at ulp(512) = 6.1e-5 by
// the +||z||^2 addition -> any code within 2*ulp of the partial min can win.
// fp32 screen error ~1e-7:            TAU  = 2*6.104e-5 + slack
// bf16x3 MFMA screen error ~2.4e-5:   TAU2 = 2*6.104e-5 + 2*2.4e-5 + slack
#define TAU  1.5e-4f
#define TAU2 2.0e-4f

// ---------------------------------------------------------------------------
// ||e_k||^2: fp64 accumulation of fp32 (e*e) terms, rounded once to fp32.
// Also zeroes the flag counter.
__global__ __launch_bounds__(256) void enorm_kernel(const float* __restrict__ e,
                                                    float* __restrict__ enorm,
                                                    int* __restrict__ count, int K) {
    if (blockIdx.x == 0 && threadIdx.x == 0 && count) *count = 0;
    int w = (blockIdx.x * 256 + threadIdx.x) >> 6;
    int lane = threadIdx.x & 63;
    if (w >= K) return;
    const float4* e4 = (const float4*)(e + (size_t)w * DIM);
    float4 a = e4[lane];
    float4 b = e4[lane + 64];
    float t0 = a.x*a.x, t1 = a.y*a.y, t2 = a.z*a.z, t3 = a.w*a.w;
    float t4 = b.x*b.x, t5 = b.y*b.y, t6 = b.z*b.z, t7 = b.w*b.w;
    double s = ((double)t0 + (double)t1) + ((double)t2 + (double)t3)
             + ((double)t4 + (double)t5) + ((double)t6 + (double)t7);
    #pragma unroll
    for (int off = 32; off > 0; off >>= 1) s += __shfl_down(s, off, 64);
    if (lane == 0) enorm[w] = (float)s;
}

// ---------------------------------------------------------------------------
// bf16 split helpers (RNE; data is finite, no NaN/Inf handling needed)
__device__ __forceinline__ ushort bf16_rne(float x) {
    uint32_t u = __float_as_uint(x);
    uint32_t r = (u + 0x7fffu + ((u >> 16) & 1u)) >> 16;
    return (ushort)r;
}
__device__ __forceinline__ float bf16_f(ushort h) {
    return __uint_as_float(((uint32_t)h) << 16);
}

// Pre-convert z and e to bf16 hi/lo pairs (memory-bound, ~50us).
__global__ __launch_bounds__(256) void cvt_kernel(const float* __restrict__ z,
                                                  const float* __restrict__ e,
                                                  ushort* __restrict__ zh, ushort* __restrict__ zl,
                                                  ushort* __restrict__ eh, ushort* __restrict__ el,
                                                  long nz4, long ne4) {
    long total = nz4 + ne4;
    for (long i = (long)blockIdx.x * 256 + threadIdx.x; i < total;
         i += (long)gridDim.x * 256) {
        const float4* s; ushort* dh; ushort* dl; long j;
        if (i < nz4) { s = (const float4*)z; dh = zh; dl = zl; j = i; }
        else         { s = (const float4*)e; dh = eh; dl = el; j = i - nz4; }
        float4 v = s[j];
        ushort h0 = bf16_rne(v.x), h1 = bf16_rne(v.y);
        ushort h2 = bf16_rne(v.z), h3 = bf16_rne(v.w);
        ushort l0 = bf16_rne(v.x - bf16_f(h0));
        ushort l1 = bf16_rne(v.y - bf16_f(h1));
        ushort l2 = bf16_rne(v.z - bf16_f(h2));
        ushort l3 = bf16_rne(v.w - bf16_f(h3));
        *(ushort4*)(dh + j * 4) = make_ushort4(h0, h1, h2, h3);
        *(ushort4*)(dl + j * 4) = make_ushort4(l0, l1, l2, l3);
    }
}

// ---------------------------------------------------------------------------
// MFMA screen: D[code][zrow] = e.z via 3-product bf16 split.
// Block: 256 thr = 4 waves (wm=codes-half, wn=zrows-half); tile 128x128.
// LDS: 4 fragment-contiguous tiles (eh,el,zh,zl), each 128x64 bf16 = 16KB,
// staged with global_load_lds width=16; frag = 64 lanes x 16B so reads AND
// writes are conflict-free by construction. Red arrays alias tile memory
// after the kt loop (64KB static-LDS budget).
using bf16x8 = __attribute__((ext_vector_type(8))) __bf16;
using f32x4  = __attribute__((ext_vector_type(4))) float;

#define GLOAD16(gp, lp) __builtin_amdgcn_global_load_lds( \
    (__attribute__((address_space(1))) void*)(void*)(gp),  \
    (__attribute__((address_space(3))) void*)(void*)(lp), 16, 0, 0)

__global__ __launch_bounds__(256, 2) void vq_mfma_kernel(
        const ushort* __restrict__ zh, const ushort* __restrict__ zl,
        const ushort* __restrict__ eh, const ushort* __restrict__ el,
        const float* __restrict__ enorm, const float* __restrict__ e,
        float* __restrict__ out, int* __restrict__ count, int* __restrict__ list,
        int cap, int N, int K) {
    __shared__ __align__(16) ushort tiles[4][8192];   // 64 KB total

    const int tid = threadIdx.x;
    const int w = tid >> 6, lane = tid & 63;
    const int wm = w >> 1, wn = w & 1;
    const int n0 = blockIdx.x * 128;

    const ushort* tsrc = (w == 0) ? eh : (w == 1) ? el : (w == 2) ? zh : zl;
    const bool is_e = (w < 2);
    const int lane_e = (lane & 15) * DIM + (lane >> 4) * 8;  // per-lane frag offset

    const bf16x8* EHf = (const bf16x8*)tiles[0];
    const bf16x8* ELf = (const bf16x8*)tiles[1];
    const bf16x8* ZHf = (const bf16x8*)tiles[2];
    const bf16x8* ZLf = (const bf16x8*)tiles[3];

    float bv[4], sv[4]; int bi[4];
    #pragma unroll
    for (int b = 0; b < 4; b++) { bv[b] = 3.4e38f; sv[b] = 3.4e38f; bi[b] = 0; }

    for (int kt = 0; kt < K; kt += 128) {
        f32x4 acc[4][4];
        const f32x4 zero4 = {0.f, 0.f, 0.f, 0.f};
        #pragma unroll
        for (int a = 0; a < 4; a++)
            #pragma unroll
            for (int b = 0; b < 4; b++) acc[a][b] = zero4;

        const int rb = is_e ? kt : n0;
        for (int d0 = 0; d0 < DIM; d0 += 64) {
            // stage: wave w loads its tile's 16 frags (mf 0..7 x c 0..1)
            const ushort* gb = tsrc + (size_t)rb * DIM + d0 + lane_e;
            #pragma unroll
            for (int f = 0; f < 16; f++) {
                GLOAD16(gb + (f >> 1) * (16 * DIM) + (f & 1) * 32,
                        &tiles[w][f * 512]);
            }
            __syncthreads();   // drains vmcnt (m97 pattern) + barrier
            #pragma unroll
            for (int c = 0; c < 2; c++) {
                bf16x8 Ah[4], Al[4];
                #pragma unroll
                for (int a = 0; a < 4; a++) {
                    int f = (wm * 4 + a) * 2 + c;
                    Ah[a] = EHf[f * 64 + lane];
                    Al[a] = ELf[f * 64 + lane];
                }
                #pragma unroll
                for (int b = 0; b < 4; b++) {
                    int f = (wn * 4 + b) * 2 + c;
                    bf16x8 Bh = ZHf[f * 64 + lane];
                    bf16x8 Bl = ZLf[f * 64 + lane];
                    #pragma unroll
                    for (int a = 0; a < 4; a++) {
                        acc[a][b] = __builtin_amdgcn_mfma_f32_16x16x32_bf16(Ah[a], Bh, acc[a][b], 0, 0, 0);
                        acc[a][b] = __builtin_amdgcn_mfma_f32_16x16x32_bf16(Al[a], Bh, acc[a][b], 0, 0, 0);
                        acc[a][b] = __builtin_amdgcn_mfma_f32_16x16x32_bf16(Ah[a], Bl, acc[a][b], 0, 0, 0);
                    }
                }
            }
            __syncthreads();
        }
        // epilogue: s = ||e||^2 - 2*dot; per-lane codes scan ascending (a outer,
        // r inner) so plain (s < bv) keeps first-min within this lane.
        const int hi4 = (lane >> 4) * 4;
        #pragma unroll
        for (int a = 0; a < 4; a++) {
            #pragma unroll
            for (int r = 0; r < 4; r++) {
                const int code = kt + wm * 64 + a * 16 + hi4 + r;
                const float en = enorm[code];   // 4KB, L1-resident
                #pragma unroll
                for (int b = 0; b < 4; b++) {
                    float s = fmaf(-2.f, acc[a][b][r], en);
                    if (s < bv[b]) { sv[b] = bv[b]; bv[b] = s; bi[b] = code; }
                    else if (s < sv[b]) sv[b] = s;
                }
            }
        }
    }

    // merge across the 4 hi-groups (lanes l, l^16, l^32, l^48 share zrows);
    // lexicographic (val, idx) preserves first-min across interleaved codes.
    #pragma unroll
    for (int off = 16; off <= 32; off <<= 1) {
        #pragma unroll
        for (int b = 0; b < 4; b++) {
            float obv = __shfl_xor(bv[b], off, 64);
            float osv = __shfl_xor(sv[b], off, 64);
            int   obi = __shfl_xor(bi[b], off, 64);
            if (obv < bv[b] || (obv == bv[b] && obi < bi[b])) {
                sv[b] = fminf(osv, fminf(sv[b], bv[b]));
                bv[b] = obv; bi[b] = obi;
            } else {
                sv[b] = fminf(sv[b], fminf(osv, obv));
            }
        }
    }

    // union: red arrays alias tile memory (tiles dead after last d0 barrier)
    char* ub = (char*)tiles;
    float* redv = (float*)ub;            // [128][2]
    float* reds = (float*)(ub + 1024);   // [128][2]
    int*   redi = (int*)  (ub + 2048);   // [128][2]
    int*   bestk = (int*) (ub + 3072);   // [128]

    if (lane < 16) {
        #pragma unroll
        for (int b = 0; b < 4; b++) {
            int rl = wn * 64 + b * 16 + lane;
            redv[rl * 2 + wm] = bv[b];
            reds[rl * 2 + wm] = sv[b];
            redi[rl * 2 + wm] = bi[b];
        }
    }
    __syncthreads();
    if (tid < 128) {
        float v  = redv[tid * 2 + 0], s2  = reds[tid * 2 + 0];
        int   ix = redi[tid * 2 + 0];
        float v2 = redv[tid * 2 + 1], s22 = reds[tid * 2 + 1];
        int   i2 = redi[tid * 2 + 1];
        if (v2 < v || (v2 == v && i2 < ix)) {
            s2 = fminf(s22, fminf(s2, v)); v = v2; ix = i2;
        } else {
            s2 = fminf(s2, fminf(s22, v2));
        }
        bestk[tid] = ix;
        if (count && (s2 - v < TAU2)) {   // quantized argmin may differ -> flag
            int slot = atomicAdd(count, 1);
            if (slot < cap) list[slot] = n0 + tid;
        }
    }
    __syncthreads();

    // Gather: out[row] = e[bestk[row]]
    const float4* e4 = (const float4*)e;
    float4* o4 = (float4*)out;
    for (int j = tid; j < 128 * (DIM / 4); j += 256) {
        int row = j >> 7;
        int col = j & 127;
        o4[(size_t)(n0 + row) * (DIM / 4) + col] = e4[(size_t)bestk[row] * (DIM / 4) + col];
    }
}

// ---------------------------------------------------------------------------
// fp32 fallback screen (previous best kernel) — used only when ws is too small
// for the bf16 workspace.
__global__ __launch_bounds__(256, 2) void vq_kernel(const float* __restrict__ z,
                                                    const float* __restrict__ e,
                                                    const float* __restrict__ enorm,
                                                    float* __restrict__ out,
                                                    int* __restrict__ count,
                                                    int* __restrict__ list,
                                                    int cap, int N, int K) {
    __shared__ __align__(16) float zs[BD * LDP];
    __shared__ __align__(16) float es[BD * LDP];
    __shared__ float redv[BM * 16];
    __shared__ int   redi[BM * 16];
    __shared__ float reds[BM * 16];
    __shared__ int   bestk[BM];

    const int tid = threadIdx.x;
    const int tx = tid & 15;
    const int ty = tid >> 4;
    const int n0 = blockIdx.x * BM;

    float bv[8], sv[8];
    int   bi[8];
    #pragma unroll
    for (int i = 0; i < 8; i++) { bv[i] = 3.4e38f; sv[i] = 3.4e38f; bi[i] = 0; }

    for (int kt = 0; kt < K; kt += BK) {
        float acc[8][8];
        #pragma unroll
        for (int i = 0; i < 8; i++)
            #pragma unroll
            for (int j = 0; j < 8; j++) acc[i][j] = 0.f;

        for (int d0 = 0; d0 < DIM; d0 += BD) {
            #pragma unroll
            for (int l = 0; l < 4; l++) {
                int j = tid + l * 256;
                int row = j >> 3;
                int c = j & 7;
                float4 v = *(const float4*)(z + (size_t)(n0 + row) * DIM + d0 + c * 4);
                zs[(c*4+0)*LDP + row] = v.x;
                zs[(c*4+1)*LDP + row] = v.y;
                zs[(c*4+2)*LDP + row] = v.z;
                zs[(c*4+3)*LDP + row] = v.w;
                float4 w = *(const float4*)(e + (size_t)(kt + row) * DIM + d0 + c * 4);
                es[(c*4+0)*LDP + row] = w.x;
                es[(c*4+1)*LDP + row] = w.y;
                es[(c*4+2)*LDP + row] = w.z;
                es[(c*4+3)*LDP + row] = w.w;
            }
            __syncthreads();
            #pragma unroll 8
            for (int dd = 0; dd < BD; dd++) {
                float4 z0 = *(const float4*)&zs[dd*LDP + ty*8];
                float4 z1 = *(const float4*)&zs[dd*LDP + ty*8+4];
                float4 e0 = *(const float4*)&es[dd*LDP + tx*4];
                float4 e1 = *(const float4*)&es[dd*LDP + tx*4+64];
                float zr[8] = {z0.x, z0.y, z0.z, z0.w, z1.x, z1.y, z1.z, z1.w};
                float ek[8] = {e0.x, e0.y, e0.z, e0.w, e1.x, e1.y, e1.z, e1.w};
                #pragma unroll
                for (int i = 0; i < 8; i++)
                    #pragma unroll
                    for (int jj = 0; jj < 8; jj++)
                        acc[i][jj] = fmaf(zr[i], ek[jj], acc[i][jj]);
            }
            __syncthreads();
        }
        #pragma unroll
        for (int jj = 0; jj < 8; jj++) {
            int kk = kt + ((jj < 4) ? (tx*4 + jj) : (64 + tx*4 + (jj - 4)));
            float en = enorm[kk];
            #pragma unroll
            for (int i = 0; i < 8; i++) {
                float s = fmaf(-2.f, acc[i][jj], en);
                if (s < bv[i]) { sv[i] = bv[i]; bv[i] = s; bi[i] = kk; }
                else if (s < sv[i]) sv[i] = s;
            }
        }
    }

    #pragma unroll
    for (int i = 0; i < 8; i++) {
        int row = ty*8 + i;
        redv[row*16 + tx] = bv[i];
        redi[row*16 + tx] = bi[i];
        reds[row*16 + tx] = sv[i];
    }
    __syncthreads();
    if (tid < BM) {
        float v = redv[tid*16];
        int ix = redi[tid*16];
        float s2 = reds[tid*16];
        #pragma unroll
        for (int t = 1; t < 16; t++) {
            float v2 = redv[tid*16 + t];
            int i2 = redi[tid*16 + t];
            float s22 = reds[tid*16 + t];
            if (v2 < v || (v2 == v && i2 < ix)) { s2 = fminf(s22, v); v = v2; ix = i2; }
            else { s2 = fminf(s2, v2); }
        }
        bestk[tid] = ix;
        if (count && (s2 - v < TAU)) {
            int slot = atomicAdd(count, 1);
            if (slot < cap) list[slot] = n0 + tid;
        }
    }
    __syncthreads();

    const float4* e4 = (const float4*)e;
    float4* o4 = (float4*)out;
    for (int j = tid; j < BM * (DIM / 4); j += 256) {
        int row = j >> 7;
        int col = j & 127;
        o4[(size_t)(n0 + row) * (DIM / 4) + col] = e4[(size_t)bestk[row] * (DIM / 4) + col];
    }
}

// ---------------------------------------------------------------------------
// Replicated-quantization re-argmin for flagged rows (exact vs reference).
__global__ __launch_bounds__(256) void fixup_kernel(const float* __restrict__ z,
                                                    const float* __restrict__ e,
                                                    const float* __restrict__ enorm,
                                                    float* __restrict__ out,
                                                    const int* __restrict__ count,
                                                    const int* __restrict__ list,
                                                    int cap, int K) {
    __shared__ double zd[DIM];
    __shared__ float Zrow;
    __shared__ float rv[256];
    __shared__ int   ri[256];
    if (!count) return;
    int cnt = *count;
    if (cnt > cap) cnt = cap;
    for (int li = blockIdx.x; li < cnt; li += gridDim.x) {
        int row = list[li];
        __syncthreads();
        for (int j = threadIdx.x; j < DIM; j += 256) zd[j] = (double)z[(size_t)row*DIM + j];
        __syncthreads();
        if (threadIdx.x == 0) {
            double s = 0.0;
            for (int j = 0; j < DIM; j++) {
                float f = (float)zd[j];
                float t = f * f;
                s += (double)t;
            }
            Zrow = (float)s;
        }
        __syncthreads();
        float Zs = Zrow;
        float best = 3.4e38f;
        int bidx = 0x7fffffff;
        for (int c = threadIdx.x; c < K; c += 256) {
            const float4* er4 = (const float4*)(e + (size_t)c * DIM);
            double s = 0.0;
            #pragma unroll 4
            for (int d4 = 0; d4 < DIM/4; d4++) {
                float4 v = er4[d4];
                s = fma(zd[d4*4+0], (double)v.x, s);
                s = fma(zd[d4*4+1], (double)v.y, s);
                s = fma(zd[d4*4+2], (double)v.z, s);
                s = fma(zd[d4*4+3], (double)v.w, s);
            }
            float m = (float)s;
            float T = Zs + enorm[c];
            float D = T - 2.0f * m;
            if (D < best) { best = D; bidx = c; }
        }
        rv[threadIdx.x] = best;
        ri[threadIdx.x] = bidx;
        __syncthreads();
        for (int st = 128; st > 0; st >>= 1) {
            if (threadIdx.x < st) {
                float v2 = rv[threadIdx.x + st];
                int    i2 = ri[threadIdx.x + st];
                if (v2 < rv[threadIdx.x] ||
                    (v2 == rv[threadIdx.x] && i2 < ri[threadIdx.x])) {
                    rv[threadIdx.x] = v2;
                    ri[threadIdx.x] = i2;
                }
            }
            __syncthreads();
        }
        int bk = ri[0];
        const float4* src = (const float4*)(e + (size_t)bk * DIM);
        float4* dst = (float4*)(out + (size_t)row * DIM);
        for (int j = threadIdx.x; j < DIM/4; j += 256) dst[j] = src[j];
    }
}

// ---------------------------------------------------------------------------
extern "C" void kernel_launch(void* const* d_in, const int* in_sizes, int n_in,
                              void* d_out, int out_size, void* d_ws, size_t ws_size,
                              hipStream_t stream) {
    const float* z = (const float*)d_in[0];
    const float* e = (const float*)d_in[1];
    float* out = (float*)d_out;
    const int N = in_sizes[0] / DIM;   // 65536
    const int K = in_sizes[1] / DIM;   // 1024

    // ws layout: [0,K) enorm | [K] count | [K+1,K+1+N) list | 4KB-aligned:
    //            zh[N*D] zl[N*D] eh[K*D] el[K*D]  (bf16 as ushort)
    float* enorm = (float*)d_ws;
    long ws_elems = (long)(ws_size / 4);
    bool have_list = ws_elems >= K + 2;
    int* count = have_list ? ((int*)d_ws + K) : nullptr;
    int* list  = have_list ? ((int*)d_ws + K + 1) : nullptr;

    size_t base_b  = (size_t)(K + 1 + N) * 4;
    size_t cvt_off = (base_b + 4095) & ~(size_t)4095;
    size_t zpart   = (size_t)N * DIM * 2;
    size_t epart   = (size_t)K * DIM * 2;
    size_t need    = cvt_off + 2 * zpart + 2 * epart;
    bool mfma_ok = have_list && ws_size >= need && K == 1024 && (N % 128) == 0;

    if (mfma_ok) {
        int cap = N;   // list region sized N ints, disjoint from bf16 region
        ushort* zh = (ushort*)((char*)d_ws + cvt_off);
        ushort* zl = zh + (size_t)N * DIM;
        ushort* eh = zl + (size_t)N * DIM;
        ushort* el = eh + (size_t)K * DIM;
        long nz4 = (long)N * (DIM / 4), ne4 = (long)K * (DIM / 4);
        cvt_kernel<<<dim3(2048), dim3(256), 0, stream>>>(z, e, zh, zl, eh, el, nz4, ne4);
        enorm_kernel<<<dim3((K + 3) / 4), dim3(256), 0, stream>>>(e, enorm, count, K);
        vq_mfma_kernel<<<dim3(N / 128), dim3(256), 0, stream>>>(zh, zl, eh, el, enorm, e,
                                                                out, count, list, cap, N, K);
        fixup_kernel<<<dim3(512), dim3(256), 0, stream>>>(z, e, enorm, out, count, list, cap, K);
    } else {
        long cap_l = have_list ? (ws_elems - K - 1) : 0;
        int cap = cap_l > N ? N : (int)cap_l;
        enorm_kernel<<<dim3((K + 3) / 4), dim3(256), 0, stream>>>(e, enorm, count, K);
        vq_kernel<<<dim3(N / BM), dim3(256), 0, stream>>>(z, e, enorm, out, count, list, cap, N, K);
        fixup_kernel<<<dim3(512), dim3(256), 0, stream>>>(z, e, enorm, out, count, list, cap, K);
    }
}

// Round 3
// 871.135 us; speedup vs baseline: 1.1424x; 1.1424x over previous
//
#include <hip/hip_runtime.h>
#include <stdint.h>

#define DIM 512
#define BM 128    // rows per workgroup (fp32 fallback)
#define BK 128    // codebook entries per k-tile (fp32 fallback)
#define BD 32     // D-chunk staged in LDS (fp32 fallback)
#define LDP 132   // padded LDS leading dim (floats, fp32 fallback)
// Flag thresholds: reference distances are quantized at ulp(512) = 6.1e-5 by
// the +||z||^2 addition -> any code within 2*ulp of the partial min can win.
// fp32 screen error ~1e-7:            TAU  = 2*6.104e-5 + slack
// bf16x3 MFMA screen error ~2.4e-5:   TAU2 = 2*6.104e-5 + 2*2.4e-5 + slack
#define TAU  1.5e-4f
#define TAU2 2.0e-4f

typedef __attribute__((ext_vector_type(8))) __bf16 bf16x8;
typedef __attribute__((ext_vector_type(4))) float  f32x4;

// ---------------------------------------------------------------------------
// ||e_k||^2: fp64 accumulation of fp32 (e*e) terms, rounded once to fp32.
// Also zeroes the flag counter.
__global__ __launch_bounds__(256) void enorm_kernel(const float* __restrict__ e,
                                                    float* __restrict__ enorm,
                                                    int* __restrict__ count, int K) {
    if (blockIdx.x == 0 && threadIdx.x == 0 && count) *count = 0;
    int w = (blockIdx.x * 256 + threadIdx.x) >> 6;
    int lane = threadIdx.x & 63;
    if (w >= K) return;
    const float4* e4 = (const float4*)(e + (size_t)w * DIM);
    float4 a = e4[lane];
    float4 b = e4[lane + 64];
    float t0 = a.x*a.x, t1 = a.y*a.y, t2 = a.z*a.z, t3 = a.w*a.w;
    float t4 = b.x*b.x, t5 = b.y*b.y, t6 = b.z*b.z, t7 = b.w*b.w;
    double s = ((double)t0 + (double)t1) + ((double)t2 + (double)t3)
             + ((double)t4 + (double)t5) + ((double)t6 + (double)t7);
    #pragma unroll
    for (int off = 32; off > 0; off >>= 1) s += __shfl_down(s, off, 64);
    if (lane == 0) enorm[w] = (float)s;
}

// ---------------------------------------------------------------------------
// bf16 split helpers (RNE; data is finite, no NaN/Inf handling needed)
__device__ __forceinline__ ushort bf16_rne(float x) {
    uint32_t u = __float_as_uint(x);
    uint32_t r = (u + 0x7fffu + ((u >> 16) & 1u)) >> 16;
    return (ushort)r;
}
__device__ __forceinline__ float bf16_f(ushort h) {
    return __uint_as_float(((uint32_t)h) << 16);
}

// Pre-convert z and e to bf16 hi/lo pairs (memory-bound).
__global__ __launch_bounds__(256) void cvt_kernel(const float* __restrict__ z,
                                                  const float* __restrict__ e,
                                                  ushort* __restrict__ zh, ushort* __restrict__ zl,
                                                  ushort* __restrict__ eh, ushort* __restrict__ el,
                                                  long nz4, long ne4) {
    long total = nz4 + ne4;
    for (long i = (long)blockIdx.x * 256 + threadIdx.x; i < total;
         i += (long)gridDim.x * 256) {
        const float4* s; ushort* dh; ushort* dl; long j;
        if (i < nz4) { s = (const float4*)z; dh = zh; dl = zl; j = i; }
        else         { s = (const float4*)e; dh = eh; dl = el; j = i - nz4; }
        float4 v = s[j];
        ushort h0 = bf16_rne(v.x), h1 = bf16_rne(v.y);
        ushort h2 = bf16_rne(v.z), h3 = bf16_rne(v.w);
        ushort l0 = bf16_rne(v.x - bf16_f(h0));
        ushort l1 = bf16_rne(v.y - bf16_f(h1));
        ushort l2 = bf16_rne(v.z - bf16_f(h2));
        ushort l3 = bf16_rne(v.w - bf16_f(h3));
        *(ushort4*)(dh + j * 4) = make_ushort4(h0, h1, h2, h3);
        *(ushort4*)(dl + j * 4) = make_ushort4(l0, l1, l2, l3);
    }
}

// ---------------------------------------------------------------------------
// MFMA screen: D[code][zrow] = e.z via 3-product bf16 split.
// Block: 256 thr = 4 waves (wm=code-half, wn=zrow-half); tile 128x128.
// LDS: 4 tiles (eh,el,zh,zl), each [128 rows][64 k] ushort, with T2-style
// XOR swizzle: element (row, kg*8..+7) at row*64 + ((kg ^ (row&7))*8).
// Reg-staged: coalesced global_load_dwordx4 -> ds_write_b128 to swizzled
// addresses; fragment ds_read_b128 uses the same swizzle -> write and read
// are address-matched by construction, both conflict-free (2-way max).
__global__ __launch_bounds__(256, 2) void vq_mfma_kernel(
        const ushort* __restrict__ zh, const ushort* __restrict__ zl,
        const ushort* __restrict__ eh, const ushort* __restrict__ el,
        const float* __restrict__ enorm, const float* __restrict__ e,
        float* __restrict__ out, int* __restrict__ count, int* __restrict__ list,
        int cap, int N, int K) {
    __shared__ __align__(16) ushort tiles[4][8192];   // 64 KB total

    const int tid = threadIdx.x;
    const int w = tid >> 6, lane = tid & 63;
    const int wm = w >> 1, wn = w & 1;
    const int n0 = blockIdx.x * 128;

    const ushort* tsrc = (w == 0) ? eh : (w == 1) ? el : (w == 2) ? zh : zl;
    const bool is_e = (w < 2);

    const int srow = lane >> 3;            // staging: row within 8-row group
    const int skg  = lane & 7;             // staging: k-group (8 ushorts)
    const int swz  = (skg ^ srow) * 8;     // swizzled k-offset (row&7 == srow)

    const ushort* EH = tiles[0];
    const ushort* EL = tiles[1];
    const ushort* ZH = tiles[2];
    const ushort* ZL = tiles[3];

    float bv[4], sv[4]; int bi[4];
    #pragma unroll
    for (int b = 0; b < 4; b++) { bv[b] = 3.4e38f; sv[b] = 3.4e38f; bi[b] = 0; }

    const int rsel = lane & 15;

    for (int kt = 0; kt < K; kt += 128) {
        f32x4 acc[4][4];
        const f32x4 zero4 = {0.f, 0.f, 0.f, 0.f};
        #pragma unroll
        for (int a = 0; a < 4; a++)
            #pragma unroll
            for (int b = 0; b < 4; b++) acc[a][b] = zero4;

        const int rb = is_e ? kt : n0;
        const ushort* gsrc = tsrc + (size_t)(rb + srow) * DIM;

        for (int d0 = 0; d0 < DIM; d0 += 64) {
            // ---- stage this wave's tile: 128 rows x 64 k (16 KB) ----
            const ushort* gp = gsrc + d0 + skg * 8;
            {
                float4 stg[8];
                #pragma unroll
                for (int i = 0; i < 8; i++)
                    stg[i] = *(const float4*)(gp + (size_t)(8 * i) * DIM);
                #pragma unroll
                for (int i = 0; i < 8; i++)
                    *(float4*)&tiles[w][(8 * i + srow) * 64 + swz] = stg[i];
                #pragma unroll
                for (int i = 0; i < 8; i++)
                    stg[i] = *(const float4*)(gp + (size_t)(64 + 8 * i) * DIM);
                #pragma unroll
                for (int i = 0; i < 8; i++)
                    *(float4*)&tiles[w][(64 + 8 * i + srow) * 64 + swz] = stg[i];
            }
            __syncthreads();

            // ---- MFMA: 2 k-steps of 32, 3 products each ----
            #pragma unroll
            for (int c = 0; c < 2; c++) {
                const int rkg = ((c * 4 + (lane >> 4)) ^ (lane & 7)) * 8;
                bf16x8 Ah[4], Al[4];
                #pragma unroll
                for (int a = 0; a < 4; a++) {
                    int off = (wm * 64 + a * 16 + rsel) * 64 + rkg;
                    Ah[a] = *(const bf16x8*)&EH[off];
                    Al[a] = *(const bf16x8*)&EL[off];
                }
                #pragma unroll
                for (int b = 0; b < 4; b++) {
                    int off = (wn * 64 + b * 16 + rsel) * 64 + rkg;
                    bf16x8 Bh = *(const bf16x8*)&ZH[off];
                    bf16x8 Bl = *(const bf16x8*)&ZL[off];
                    #pragma unroll
                    for (int a = 0; a < 4; a++) {
                        acc[a][b] = __builtin_amdgcn_mfma_f32_16x16x32_bf16(Ah[a], Bh, acc[a][b], 0, 0, 0);
                        acc[a][b] = __builtin_amdgcn_mfma_f32_16x16x32_bf16(Al[a], Bh, acc[a][b], 0, 0, 0);
                        acc[a][b] = __builtin_amdgcn_mfma_f32_16x16x32_bf16(Ah[a], Bl, acc[a][b], 0, 0, 0);
                    }
                }
            }
            __syncthreads();
        }
        // epilogue: s = ||e||^2 - 2*dot; per-lane codes scan ascending (a outer,
        // r inner) so plain (s < bv) keeps first-min within this lane.
        const int hi4 = (lane >> 4) * 4;
        #pragma unroll
        for (int a = 0; a < 4; a++) {
            #pragma unroll
            for (int r = 0; r < 4; r++) {
                const int code = kt + wm * 64 + a * 16 + hi4 + r;
                const float en = enorm[code];   // 4KB, L1-resident
                #pragma unroll
                for (int b = 0; b < 4; b++) {
                    float s = fmaf(-2.f, acc[a][b][r], en);
                    if (s < bv[b]) { sv[b] = bv[b]; bv[b] = s; bi[b] = code; }
                    else if (s < sv[b]) sv[b] = s;
                }
            }
        }
    }

    // merge across the 4 hi-groups (lanes l, l^16, l^32, l^48 share zrows);
    // lexicographic (val, idx) preserves first-min across interleaved codes.
    #pragma unroll
    for (int off = 16; off <= 32; off <<= 1) {
        #pragma unroll
        for (int b = 0; b < 4; b++) {
            float obv = __shfl_xor(bv[b], off, 64);
            float osv = __shfl_xor(sv[b], off, 64);
            int   obi = __shfl_xor(bi[b], off, 64);
            if (obv < bv[b] || (obv == bv[b] && obi < bi[b])) {
                sv[b] = fminf(osv, fminf(sv[b], bv[b]));
                bv[b] = obv; bi[b] = obi;
            } else {
                sv[b] = fminf(sv[b], fminf(osv, obv));
            }
        }
    }

    // union: red arrays alias tile memory (tiles dead after last d0 barrier)
    char* ub = (char*)tiles;
    float* redv = (float*)ub;            // [128][2]
    float* reds = (float*)(ub + 1024);   // [128][2]
    int*   redi = (int*)  (ub + 2048);   // [128][2]
    int*   bestk = (int*) (ub + 3072);   // [128]

    if (lane < 16) {
        #pragma unroll
        for (int b = 0; b < 4; b++) {
            int rl = wn * 64 + b * 16 + lane;
            redv[rl * 2 + wm] = bv[b];
            reds[rl * 2 + wm] = sv[b];
            redi[rl * 2 + wm] = bi[b];
        }
    }
    __syncthreads();
    if (tid < 128) {
        float v  = redv[tid * 2 + 0], s2  = reds[tid * 2 + 0];
        int   ix = redi[tid * 2 + 0];
        float v2 = redv[tid * 2 + 1], s22 = reds[tid * 2 + 1];
        int   i2 = redi[tid * 2 + 1];
        if (v2 < v || (v2 == v && i2 < ix)) {
            s2 = fminf(s22, fminf(s2, v)); v = v2; ix = i2;
        } else {
            s2 = fminf(s2, fminf(s22, v2));
        }
        bestk[tid] = ix;
        if (count && (s2 - v < TAU2)) {   // quantized argmin may differ -> flag
            int slot = atomicAdd(count, 1);
            if (slot < cap) list[slot] = n0 + tid;
        }
    }
    __syncthreads();

    // Gather: out[row] = e[bestk[row]]
    const float4* e4 = (const float4*)e;
    float4* o4 = (float4*)out;
    for (int j = tid; j < 128 * (DIM / 4); j += 256) {
        int row = j >> 7;
        int col = j & 127;
        o4[(size_t)(n0 + row) * (DIM / 4) + col] = e4[(size_t)bestk[row] * (DIM / 4) + col];
    }
}

// ---------------------------------------------------------------------------
// fp32 fallback screen (previous best kernel) — used only when ws is too small
// for the bf16 workspace.
__global__ __launch_bounds__(256, 2) void vq_kernel(const float* __restrict__ z,
                                                    const float* __restrict__ e,
                                                    const float* __restrict__ enorm,
                                                    float* __restrict__ out,
                                                    int* __restrict__ count,
                                                    int* __restrict__ list,
                                                    int cap, int N, int K) {
    __shared__ __align__(16) float zs[BD * LDP];
    __shared__ __align__(16) float es[BD * LDP];
    __shared__ float redv[BM * 16];
    __shared__ int   redi[BM * 16];
    __shared__ float reds[BM * 16];
    __shared__ int   bestk[BM];

    const int tid = threadIdx.x;
    const int tx = tid & 15;
    const int ty = tid >> 4;
    const int n0 = blockIdx.x * BM;

    float bv[8], sv[8];
    int   bi[8];
    #pragma unroll
    for (int i = 0; i < 8; i++) { bv[i] = 3.4e38f; sv[i] = 3.4e38f; bi[i] = 0; }

    for (int kt = 0; kt < K; kt += BK) {
        float acc[8][8];
        #pragma unroll
        for (int i = 0; i < 8; i++)
            #pragma unroll
            for (int j = 0; j < 8; j++) acc[i][j] = 0.f;

        for (int d0 = 0; d0 < DIM; d0 += BD) {
            #pragma unroll
            for (int l = 0; l < 4; l++) {
                int j = tid + l * 256;
                int row = j >> 3;
                int c = j & 7;
                float4 v = *(const float4*)(z + (size_t)(n0 + row) * DIM + d0 + c * 4);
                zs[(c*4+0)*LDP + row] = v.x;
                zs[(c*4+1)*LDP + row] = v.y;
                zs[(c*4+2)*LDP + row] = v.z;
                zs[(c*4+3)*LDP + row] = v.w;
                float4 w = *(const float4*)(e + (size_t)(kt + row) * DIM + d0 + c * 4);
                es[(c*4+0)*LDP + row] = w.x;
                es[(c*4+1)*LDP + row] = w.y;
                es[(c*4+2)*LDP + row] = w.z;
                es[(c*4+3)*LDP + row] = w.w;
            }
            __syncthreads();
            #pragma unroll 8
            for (int dd = 0; dd < BD; dd++) {
                float4 z0 = *(const float4*)&zs[dd*LDP + ty*8];
                float4 z1 = *(const float4*)&zs[dd*LDP + ty*8+4];
                float4 e0 = *(const float4*)&es[dd*LDP + tx*4];
                float4 e1 = *(const float4*)&es[dd*LDP + tx*4+64];
                float zr[8] = {z0.x, z0.y, z0.z, z0.w, z1.x, z1.y, z1.z, z1.w};
                float ek[8] = {e0.x, e0.y, e0.z, e0.w, e1.x, e1.y, e1.z, e1.w};
                #pragma unroll
                for (int i = 0; i < 8; i++)
                    #pragma unroll
                    for (int jj = 0; jj < 8; jj++)
                        acc[i][jj] = fmaf(zr[i], ek[jj], acc[i][jj]);
            }
            __syncthreads();
        }
        #pragma unroll
        for (int jj = 0; jj < 8; jj++) {
            int kk = kt + ((jj < 4) ? (tx*4 + jj) : (64 + tx*4 + (jj - 4)));
            float en = enorm[kk];
            #pragma unroll
            for (int i = 0; i < 8; i++) {
                float s = fmaf(-2.f, acc[i][jj], en);
                if (s < bv[i]) { sv[i] = bv[i]; bv[i] = s; bi[i] = kk; }
                else if (s < sv[i]) sv[i] = s;
            }
        }
    }

    #pragma unroll
    for (int i = 0; i < 8; i++) {
        int row = ty*8 + i;
        redv[row*16 + tx] = bv[i];
        redi[row*16 + tx] = bi[i];
        reds[row*16 + tx] = sv[i];
    }
    __syncthreads();
    if (tid < BM) {
        float v = redv[tid*16];
        int ix = redi[tid*16];
        float s2 = reds[tid*16];
        #pragma unroll
        for (int t = 1; t < 16; t++) {
            float v2 = redv[tid*16 + t];
            int i2 = redi[tid*16 + t];
            float s22 = reds[tid*16 + t];
            if (v2 < v || (v2 == v && i2 < ix)) { s2 = fminf(s22, v); v = v2; ix = i2; }
            else { s2 = fminf(s2, v2); }
        }
        bestk[tid] = ix;
        if (count && (s2 - v < TAU)) {
            int slot = atomicAdd(count, 1);
            if (slot < cap) list[slot] = n0 + tid;
        }
    }
    __syncthreads();

    const float4* e4 = (const float4*)e;
    float4* o4 = (float4*)out;
    for (int j = tid; j < BM * (DIM / 4); j += 256) {
        int row = j >> 7;
        int col = j & 127;
        o4[(size_t)(n0 + row) * (DIM / 4) + col] = e4[(size_t)bestk[row] * (DIM / 4) + col];
    }
}

// ---------------------------------------------------------------------------
// Replicated-quantization re-argmin for flagged rows (exact vs reference):
//   D_k = fl32( fl32(Z + E_k) - 2 * fl32(dot64) ),  argmin, first-index ties.
// Z = fl32 of an all-fp64 sum of fp32 (z*z) terms; summation order differs
// from numpy's pairwise but fp64 error (~1e-11) is far below ulp(512)=6.1e-5,
// and the TAU-screen absorbs ulp-level Z differences.
__global__ __launch_bounds__(256) void fixup_kernel(const float* __restrict__ z,
                                                    const float* __restrict__ e,
                                                    const float* __restrict__ enorm,
                                                    float* __restrict__ out,
                                                    const int* __restrict__ count,
                                                    const int* __restrict__ list,
                                                    int cap, int K) {
    __shared__ double zd[DIM];
    __shared__ double rzd[256];
    __shared__ float Zrow;
    __shared__ float rv[256];
    __shared__ int   ri[256];
    if (!count) return;
    int cnt = *count;
    if (cnt > cap) cnt = cap;
    for (int li = blockIdx.x; li < cnt; li += gridDim.x) {
        int row = list[li];
        __syncthreads();
        for (int j = threadIdx.x; j < DIM; j += 256) zd[j] = (double)z[(size_t)row*DIM + j];
        __syncthreads();
        // Z: parallel fp64 tree-sum of fp32 (z*z) terms, one final rounding.
        {
            double p = 0.0;
            for (int j = threadIdx.x; j < DIM; j += 256) {
                float f = (float)zd[j];
                float t = f * f;
                p += (double)t;
            }
            rzd[threadIdx.x] = p;
            __syncthreads();
            for (int st = 128; st > 0; st >>= 1) {
                if (threadIdx.x < st) rzd[threadIdx.x] += rzd[threadIdx.x + st];
                __syncthreads();
            }
            if (threadIdx.x == 0) Zrow = (float)rzd[0];
        }
        __syncthreads();
        float Zs = Zrow;
        float best = 3.4e38f;
        int bidx = 0x7fffffff;
        for (int c = threadIdx.x; c < K; c += 256) {   // ascending per thread
            const float4* er4 = (const float4*)(e + (size_t)c * DIM);
            double s = 0.0;
            #pragma unroll 4
            for (int d4 = 0; d4 < DIM/4; d4++) {
                float4 v = er4[d4];
                s = fma(zd[d4*4+0], (double)v.x, s);
                s = fma(zd[d4*4+1], (double)v.y, s);
                s = fma(zd[d4*4+2], (double)v.z, s);
                s = fma(zd[d4*4+3], (double)v.w, s);
            }
            float m = (float)s;              // fl32(dot)
            float T = Zs + enorm[c];         // fl32(Z + E_k)   (quantizes at ulp(512))
            float D = T - 2.0f * m;          // fl32(T - 2m)    (2m exact)
            if (D < best) { best = D; bidx = c; }
        }
        rv[threadIdx.x] = best;
        ri[threadIdx.x] = bidx;
        __syncthreads();
        for (int st = 128; st > 0; st >>= 1) {
            if (threadIdx.x < st) {
                float v2 = rv[threadIdx.x + st];
                int    i2 = ri[threadIdx.x + st];
                if (v2 < rv[threadIdx.x] ||
                    (v2 == rv[threadIdx.x] && i2 < ri[threadIdx.x])) {
                    rv[threadIdx.x] = v2;
                    ri[threadIdx.x] = i2;
                }
            }
            __syncthreads();
        }
        int bk = ri[0];
        const float4* src = (const float4*)(e + (size_t)bk * DIM);
        float4* dst = (float4*)(out + (size_t)row * DIM);
        for (int j = threadIdx.x; j < DIM/4; j += 256) dst[j] = src[j];
    }
}

// ---------------------------------------------------------------------------
extern "C" void kernel_launch(void* const* d_in, const int* in_sizes, int n_in,
                              void* d_out, int out_size, void* d_ws, size_t ws_size,
                              hipStream_t stream) {
    const float* z = (const float*)d_in[0];
    const float* e = (const float*)d_in[1];
    float* out = (float*)d_out;
    const int N = in_sizes[0] / DIM;   // 65536
    const int K = in_sizes[1] / DIM;   // 1024

    // ws layout: [0,K) enorm | [K] count | [K+1,K+1+N) list | 4KB-aligned:
    //            zh[N*D] zl[N*D] eh[K*D] el[K*D]  (bf16 as ushort)
    float* enorm = (float*)d_ws;
    long ws_elems = (long)(ws_size / 4);
    bool have_list = ws_elems >= K + 2;
    int* count = have_list ? ((int*)d_ws + K) : nullptr;
    int* list  = have_list ? ((int*)d_ws + K + 1) : nullptr;

    size_t base_b  = (size_t)(K + 1 + N) * 4;
    size_t cvt_off = (base_b + 4095) & ~(size_t)4095;
    size_t zpart   = (size_t)N * DIM * 2;
    size_t epart   = (size_t)K * DIM * 2;
    size_t need    = cvt_off + 2 * zpart + 2 * epart;
    bool mfma_ok = have_list && ws_size >= need && K == 1024 && (N % 128) == 0;

    if (mfma_ok) {
        int cap = N;   // list region sized N ints, disjoint from bf16 region
        ushort* zh = (ushort*)((char*)d_ws + cvt_off);
        ushort* zl = zh + (size_t)N * DIM;
        ushort* eh = zl + (size_t)N * DIM;
        ushort* el = eh + (size_t)K * DIM;
        long nz4 = (long)N * (DIM / 4), ne4 = (long)K * (DIM / 4);
        cvt_kernel<<<dim3(2048), dim3(256), 0, stream>>>(z, e, zh, zl, eh, el, nz4, ne4);
        enorm_kernel<<<dim3((K + 3) / 4), dim3(256), 0, stream>>>(e, enorm, count, K);
        vq_mfma_kernel<<<dim3(N / 128), dim3(256), 0, stream>>>(zh, zl, eh, el, enorm, e,
                                                                out, count, list, cap, N, K);
        fixup_kernel<<<dim3(2048), dim3(256), 0, stream>>>(z, e, enorm, out, count, list, cap, K);
    } else {
        long cap_l = have_list ? (ws_elems - K - 1) : 0;
        int cap = cap_l > N ? N : (int)cap_l;
        enorm_kernel<<<dim3((K + 3) / 4), dim3(256), 0, stream>>>(e, enorm, count, K);
        vq_kernel<<<dim3(N / BM), dim3(256), 0, stream>>>(z, e, enorm, out, count, list, cap, N, K);
        fixup_kernel<<<dim3(2048), dim3(256), 0, stream>>>(z, e, enorm, out, count, list, cap, K);
    }
}